// Round 3
// baseline (509.523 us; speedup 1.0000x reference)
//
#include <hip/hip_runtime.h>
#include <hip/hip_bf16.h>
#include <math.h>

typedef unsigned int u32;
typedef unsigned long long u64;

#define PRE_NMS    6000
#define NGROUPS    24       /* batch(8) * 3 group-id slots; only b*3+{1,2} populated */
#define HIST_WORDS 1048576  /* bits>>10 buckets */
#define KMAX       3072     /* LDS SoA capacity per group; global fallback above */
#define KPAD       3136     /* KMAX + 64 read-overrun pad */

/* ws byte offsets */
#define HIST_OFF   0
#define CTR_OFF    4194304  /* 64 u32: [0]=cand count [1]=pivot bits */
#define COARSE_OFF 4194560  /* 1024 u32 coarse histogram */
#define CAND_OFF   4198656  /* 8192 u64 unsorted candidate keys */
#define RANK_OFF   4264192  /* 8192 u64 rank-scattered (sorted) keys */
#define BOX_OFF    4329728  /* 6000 float4 group-offset boxes */
#define AREA_OFF   4425728  /* 6000 float */
#define GID_OFF    4449728  /* 6000 int group ids */

__global__ void zero_kernel(uint4* __restrict__ p, int n4) {
    int idx = blockIdx.x * blockDim.x + threadIdx.x;
    int stride = gridDim.x * blockDim.x;
    uint4 z; z.x = z.y = z.z = z.w = 0u;
    for (int i = idx; i < n4; i += stride) p[i] = z;
}

__global__ void hist_kernel(const float* __restrict__ probs, u32* __restrict__ hist, int nfg) {
    int i = blockIdx.x * blockDim.x + threadIdx.x;
    if (i >= nfg) return;
    float v = probs[(i >> 1) * 3 + 1 + (i & 1)];
    u32 bits = __float_as_uint(v);
    u32 b = bits >> 10; if (b >= HIST_WORDS) b = HIST_WORDS - 1;
    atomicAdd(&hist[b], 1u);
}

/* fold 1M fine buckets into 1024 coarse buckets, 1024 blocks x 256 thr */
__global__ __launch_bounds__(256) void coarse_kernel(const u32* __restrict__ hist,
                                                     u32* __restrict__ coarse) {
    __shared__ u32 red[4];
    int b = blockIdx.x, t = threadIdx.x;
    const uint4* h4 = (const uint4*)(hist + b * 1024);
    uint4 v = h4[t];
    u32 s = v.x + v.y + v.z + v.w;
    #pragma unroll
    for (int off = 32; off > 0; off >>= 1) s += __shfl_down(s, off);
    if ((t & 63) == 0) red[t >> 6] = s;
    __syncthreads();
    if (t == 0) coarse[b] = red[0] + red[1] + red[2] + red[3];
}

/* two 1024-wide suffix scans: coarse bucket, then fine slice */
__global__ __launch_bounds__(1024) void pivot_kernel(const u32* __restrict__ hist,
                                                     const u32* __restrict__ coarse,
                                                     u32* ctr) {
    __shared__ u32 sd[1024];
    __shared__ u32 s_cc, s_rem;
    int t = threadIdx.x;
    u32 v = coarse[1023 - t];
    sd[t] = v;
    __syncthreads();
    for (int off = 1; off < 1024; off <<= 1) {
        u32 tmp = (t >= off) ? sd[t - off] : 0u;
        __syncthreads();
        sd[t] += tmp;
        __syncthreads();
    }
    u32 incl = sd[t], excl = incl - v;
    if (incl >= (u32)PRE_NMS && excl < (u32)PRE_NMS) {
        s_cc = (u32)(1023 - t);
        s_rem = (u32)PRE_NMS - excl;
    }
    __syncthreads();
    u32 cc = s_cc, rem = s_rem;
    u32 fv = hist[cc * 1024 + 1023 - t];
    __syncthreads();
    sd[t] = fv;
    __syncthreads();
    for (int off = 1; off < 1024; off <<= 1) {
        u32 tmp = (t >= off) ? sd[t - off] : 0u;
        __syncthreads();
        sd[t] += tmp;
        __syncthreads();
    }
    incl = sd[t]; excl = incl - fv;
    if (incl >= rem && excl < rem)
        ctr[1] = ((cc << 10) + (u32)(1023 - t)) << 10;
}

__global__ void compact_kernel(const float* __restrict__ probs, u32* ctr,
                               u64* __restrict__ cand, int nfg) {
    int i = blockIdx.x * blockDim.x + threadIdx.x;
    if (i >= nfg) return;
    u32 pivot = ctr[1];
    float v = probs[(i >> 1) * 3 + 1 + (i & 1)];
    u32 bits = __float_as_uint(v);
    if (bits >= pivot) {
        u32 pos = atomicAdd(&ctr[0], 1u);
        if (pos < 8192u) cand[pos] = ((u64)bits << 32) | (u64)(~(u32)i);
    }
}

/* exact descending stable position via rank-by-counting (keys unique) */
__global__ __launch_bounds__(256) void rank_kernel(const u64* __restrict__ cand,
                                                   const u32* __restrict__ ctr,
                                                   u64* __restrict__ ranked) {
    __shared__ u64 tile[256];
    int t = threadIdx.x;
    int i = blockIdx.x * 256 + t;
    u32 M = ctr[0]; if (M > 8192u) M = 8192u;
    u64 key = (i < (int)M) ? cand[i] : 0ull;
    int rank = 0;
    for (u32 base = 0; base < M; base += 256) {
        u32 s = base + t;
        tile[t] = (s < M) ? cand[s] : 0ull;
        __syncthreads();
        #pragma unroll 8
        for (int q = 0; q < 256; ++q) rank += (tile[q] > key) ? 1 : 0;
        __syncthreads();
    }
    if (i < (int)M && rank < PRE_NMS) ranked[rank] = key;
}

__global__ void rois_kernel(const u64* __restrict__ skeys,
                            const float4* __restrict__ deltas4,
                            const float4* __restrict__ anchors4,
                            float* __restrict__ out,
                            float4* __restrict__ boxes,
                            float* __restrict__ areas,
                            int* __restrict__ gid,
                            int n_anch) {
    int s = blockIdx.x * blockDim.x + threadIdx.x;
    if (s >= PRE_NMS) return;
    u64 key = skeys[s];
    u32 bits = (u32)(key >> 32);
    u32 flat = ~((u32)key);
    float score = __uint_as_float(bits);
    int p = (int)(flat >> 1);
    int cls = (int)(flat & 1u) + 1;
    int b = p / n_anch;
    int aidx = p - b * n_anch;
    float4 a = anchors4[aidx];
    float4 d = deltas4[p];
    float d0 = d.x * 0.1f, d1 = d.y * 0.1f, d2 = d.z * 0.2f, d3 = d.w * 0.2f;
    float y1 = a.x * (1.0f / 512.0f), x1 = a.y * (1.0f / 512.0f);
    float y2 = a.z * (1.0f / 512.0f), x2 = a.w * (1.0f / 512.0f);
    float h = y2 - y1, w = x2 - x1;
    float cy = y1 + 0.5f * h + d0 * h;
    float cx = x1 + 0.5f * w + d1 * w;
    h = h * expf(d2);
    w = w * expf(d3);
    float ry1 = (cy - 0.5f * h) * 512.0f;
    float rx1 = (cx - 0.5f * w) * 512.0f;
    float ry2 = (cy - 0.5f * h + h) * 512.0f;
    float rx2 = (cx - 0.5f * w + w) * 512.0f;
    ry1 = fminf(fmaxf(ry1, 0.0f), 512.0f);
    rx1 = fminf(fmaxf(rx1, 0.0f), 512.0f);
    ry2 = fminf(fmaxf(ry2, 0.0f), 512.0f);
    rx2 = fminf(fmaxf(rx2, 0.0f), 512.0f);
    out[s * 6 + 0] = ry1;
    out[s * 6 + 1] = rx1;
    out[s * 6 + 2] = ry2;
    out[s * 6 + 3] = rx2;
    out[s * 6 + 4] = score;
    out[PRE_NMS * 6 + s] = (float)cls;
    out[PRE_NMS * 7 + s] = (float)b;
    int g = b * 3 + cls;
    float gf = (float)g * 4096.0f;
    float4 bb = make_float4(ry1 + gf, rx1 + gf, ry2 + gf, rx2 + gf);
    boxes[s] = bb;
    areas[s] = (bb.z - bb.x + 1.0f) * (bb.w - bb.y + 1.0f);
    gid[s] = g;
}

/* One block per (batch,class) group; cross-group IoU exactly 0 (offset 4096).
   Iterative greedy NMS, no mask matrix: lane l holds suppression bits for
   columns l+64k; replicated per-64-row word rebuilt via __ballot (cheap). */
__global__ __launch_bounds__(256) void group_nms_kernel(const float4* __restrict__ boxes,
                                                        const float* __restrict__ areas,
                                                        const int* __restrict__ gid,
                                                        float* __restrict__ out) {
    __shared__ unsigned short list[PRE_NMS];  /* 12 KB */
    __shared__ float y1s[KPAD], x1s[KPAD], y2s[KPAD], x2s[KPAD], ars[KPAD]; /* 61.3 KB */
    __shared__ int sK;
    int g = blockIdx.x;
    int t = threadIdx.x;
    int lane = t & 63;

    /* Phase A: stable compaction of group members (wave 0) */
    if (t < 64) {
        int k = 0;
        for (int base = 0; base < PRE_NMS; base += 64) {
            int s = base + lane;
            bool f = (s < PRE_NMS) && (gid[s] == g);
            u64 bal = __ballot(f);
            if (f) list[k + (int)__popcll(bal & ((1ull << lane) - 1ull))] = (unsigned short)s;
            k += (int)__popcll(bal);
        }
        if (lane == 0) sK = k;
    }
    __syncthreads();
    int K = sK;
    if (K == 0) return;
    int Wp = (K + 63) >> 6;

    /* Phase B: stage SoA into LDS (fast path) */
    if (K <= KMAX) {
        for (int m = t; m < K; m += 256) {
            int s = list[m];
            float4 bb = boxes[s];
            y1s[m] = bb.x; x1s[m] = bb.y; y2s[m] = bb.z; x2s[m] = bb.w;
            ars[m] = areas[s];
        }
    }
    __syncthreads();

    /* Phase C: serial greedy chain, wave 0 only */
    if (t >= 64) return;
    if (K <= KMAX) {
        u64 remv = 0ull;
        for (int w = 0; w < Wp; ++w) {
            int r0 = w << 6;
            int rend = K - r0; if (rend > 64) rend = 64;
            u64 cur = __ballot((remv >> w) & 1ull);
            u64 kb = 0ull;
            for (int b = 0; b < rend; ++b) {
                int r = r0 + b;
                bool sup = (cur >> b) & 1ull;
                kb |= (sup ? 0ull : 1ull) << b;
                if (!sup) {
                    float ry1 = y1s[r], rx1 = x1s[r], ry2 = y2s[r], rx2 = x2s[r], ra = ars[r];
                    u64 nm = 0ull;
                    for (int k = w; k < Wp; ++k) {
                        int c = (k << 6) + lane;
                        float ih = fminf(ry2, y2s[c]) - fmaxf(ry1, y1s[c]) + 1.0f;
                        float iw = fminf(rx2, x2s[c]) - fmaxf(rx1, x1s[c]) + 1.0f;
                        ih = fmaxf(ih, 0.0f); iw = fmaxf(iw, 0.0f);
                        bool o = (3.0f * ih * iw >= ra + ars[c]) && (c > r) && (c < K);
                        if (o) nm |= 1ull << k;
                    }
                    remv |= nm;
                    cur = __ballot((remv >> w) & 1ull);
                }
            }
            if (lane < rend)
                out[(int)list[r0 + lane] * 6 + 5] = ((kb >> lane) & 1ull) ? 1.0f : 0.0f;
        }
    } else {
        /* fallback: K > KMAX (never expected) — same algorithm from global mem */
        u64 remv0 = 0ull, remv1 = 0ull;
        for (int w = 0; w < Wp; ++w) {
            int r0 = w << 6;
            int rend = K - r0; if (rend > 64) rend = 64;
            u64 cur = (w < 64) ? __ballot((remv0 >> w) & 1ull)
                               : __ballot((remv1 >> (w - 64)) & 1ull);
            u64 kb = 0ull;
            for (int b = 0; b < rend; ++b) {
                int r = r0 + b;
                bool sup = (cur >> b) & 1ull;
                kb |= (sup ? 0ull : 1ull) << b;
                if (!sup) {
                    int sr = list[r];
                    float4 rb = boxes[sr];
                    float ra = areas[sr];
                    for (int k = w; k < Wp; ++k) {
                        int c = (k << 6) + lane;
                        bool o = false;
                        if (c < K && c > r) {
                            int sc = list[c];
                            float4 cb = boxes[sc];
                            float ih = fminf(rb.z, cb.z) - fmaxf(rb.x, cb.x) + 1.0f;
                            float iw = fminf(rb.w, cb.w) - fmaxf(rb.y, cb.y) + 1.0f;
                            ih = fmaxf(ih, 0.0f); iw = fmaxf(iw, 0.0f);
                            o = (3.0f * ih * iw >= ra + areas[sc]);
                        }
                        if (o) { if (k < 64) remv0 |= 1ull << k; else remv1 |= 1ull << (k - 64); }
                    }
                    cur = (w < 64) ? __ballot((remv0 >> w) & 1ull)
                                   : __ballot((remv1 >> (w - 64)) & 1ull);
                }
            }
            if (lane < rend)
                out[(int)list[r0 + lane] * 6 + 5] = ((kb >> lane) & 1ull) ? 1.0f : 0.0f;
        }
    }
}

extern "C" void kernel_launch(void* const* d_in, const int* in_sizes, int n_in,
                              void* d_out, int out_size, void* d_ws, size_t ws_size,
                              hipStream_t stream) {
    const float* probs   = (const float*)d_in[0];
    const float* deltas  = (const float*)d_in[1];
    const float* anchors = (const float*)d_in[2];
    int n_prop = in_sizes[1] / 4;        /* 522240 */
    int n_anch = in_sizes[2] / 4;        /* 65280  */
    int nfg    = n_prop * 2;             /* 1044480 */

    char* ws = (char*)d_ws;
    u32*    hist   = (u32*)(ws + HIST_OFF);
    u32*    ctr    = (u32*)(ws + CTR_OFF);
    u32*    coarse = (u32*)(ws + COARSE_OFF);
    u64*    cand   = (u64*)(ws + CAND_OFF);
    u64*    ranked = (u64*)(ws + RANK_OFF);
    float4* boxes  = (float4*)(ws + BOX_OFF);
    float*  areas  = (float*)(ws + AREA_OFF);
    int*    gid    = (int*)(ws + GID_OFF);
    float*  out    = (float*)d_out;

    /* zero hist + ctr: (1048576 + 64) u32 = 262160 uint4 */
    zero_kernel<<<1024, 256, 0, stream>>>((uint4*)(ws + HIST_OFF), 262160);
    hist_kernel<<<(nfg + 255) / 256, 256, 0, stream>>>(probs, hist, nfg);
    coarse_kernel<<<1024, 256, 0, stream>>>(hist, coarse);
    pivot_kernel<<<1, 1024, 0, stream>>>(hist, coarse, ctr);
    compact_kernel<<<(nfg + 255) / 256, 256, 0, stream>>>(probs, ctr, cand, nfg);
    rank_kernel<<<32, 256, 0, stream>>>(cand, ctr, ranked);
    rois_kernel<<<(PRE_NMS + 255) / 256, 256, 0, stream>>>(
        ranked, (const float4*)deltas, (const float4*)anchors, out, boxes, areas, gid, n_anch);
    group_nms_kernel<<<NGROUPS, 256, 0, stream>>>(boxes, areas, gid, out);
}

// Round 5
// 360.735 us; speedup vs baseline: 1.4125x; 1.4125x over previous
//
#include <hip/hip_runtime.h>
#include <hip/hip_bf16.h>
#include <math.h>

typedef unsigned int u32;
typedef unsigned long long u64;

#define PRE_NMS 6000
#define NGROUPS 24       /* b*3+cls slots; only cls 1,2 populated */
#define NBLK    94       /* ceil(6000/64) */
#define KMAX    512      /* fast-path group capacity (E[K]=375, sigma~19) */
#define WMAX    8

/* ws byte offsets */
#define CTR_OFF    0        /* 64 u32: [0]=cand cnt [1]=pivot bits [2]=cc [3]=rem */
#define COARSE_OFF 256      /* 1024 u32 */
#define FINE_OFF   4352     /* 1024 u32 */
#define CAND_OFF   8448     /* 8192 u64 */
#define RANK_OFF   73984    /* 8192 u64 */
#define BOX_OFF    139520   /* 6000 float4 */
#define AREA_OFF   235520   /* 6000 float */
#define GID_OFF    259520   /* 6000 int */

__global__ void zero_kernel(uint4* __restrict__ p, int n4) {
    int i = blockIdx.x * blockDim.x + threadIdx.x;
    uint4 z; z.x = z.y = z.z = z.w = 0u;
    if (i < n4) p[i] = z;
}

/* coarse histogram of bits>>20 (scores<1 => <=0x3F8), 4 LDS copies vs contention */
__global__ __launch_bounds__(1024) void coarse_hist_kernel(const float* __restrict__ probs,
                                                           u32* __restrict__ coarse, int nfg) {
    __shared__ u32 h[4][1024];
    int t = threadIdx.x;
    int copy = t >> 8;
    for (int i = t; i < 4096; i += 1024) ((u32*)h)[i] = 0u;
    __syncthreads();
    int idx = blockIdx.x * 1024 + t;
    int stride = gridDim.x * 1024;
    for (int i = idx; i < nfg; i += stride) {
        float v = probs[(i >> 1) * 3 + 1 + (i & 1)];
        u32 b = __float_as_uint(v) >> 20; if (b > 1023u) b = 1023u;
        atomicAdd(&h[copy][b], 1u);
    }
    __syncthreads();
    u32 s = h[0][t] + h[1][t] + h[2][t] + h[3][t];
    if (s) atomicAdd(&coarse[t], s);
}

/* suffix scan from top over coarse buckets -> cc, rem */
__global__ __launch_bounds__(1024) void pivot1_kernel(const u32* __restrict__ coarse, u32* ctr) {
    __shared__ u32 sd[1024];
    int t = threadIdx.x;
    u32 v = coarse[1023 - t];
    sd[t] = v;
    __syncthreads();
    for (int off = 1; off < 1024; off <<= 1) {
        u32 tmp = (t >= off) ? sd[t - off] : 0u;
        __syncthreads();
        sd[t] += tmp;
        __syncthreads();
    }
    u32 incl = sd[t], excl = incl - v;
    if (incl >= (u32)PRE_NMS && excl < (u32)PRE_NMS) {
        ctr[2] = (u32)(1023 - t);
        ctr[3] = (u32)PRE_NMS - excl;
    }
}

/* fine histogram of (bits>>10)&1023 restricted to coarse bucket cc */
__global__ __launch_bounds__(1024) void fine_hist_kernel(const float* __restrict__ probs,
                                                         const u32* __restrict__ ctr,
                                                         u32* __restrict__ fine, int nfg) {
    __shared__ u32 h[4][1024];
    int t = threadIdx.x;
    int copy = t >> 8;
    for (int i = t; i < 4096; i += 1024) ((u32*)h)[i] = 0u;
    __syncthreads();
    u32 cc = ctr[2];
    int idx = blockIdx.x * 1024 + t;
    int stride = gridDim.x * 1024;
    for (int i = idx; i < nfg; i += stride) {
        float v = probs[(i >> 1) * 3 + 1 + (i & 1)];
        u32 bits = __float_as_uint(v);
        u32 b = bits >> 20; if (b > 1023u) b = 1023u;
        if (b == cc) atomicAdd(&h[copy][(bits >> 10) & 1023u], 1u);
    }
    __syncthreads();
    u32 s = h[0][t] + h[1][t] + h[2][t] + h[3][t];
    if (s) atomicAdd(&fine[t], s);
}

/* suffix scan over fine buckets -> pivot bits (identical value to prior rounds) */
__global__ __launch_bounds__(1024) void pivot2_kernel(const u32* __restrict__ fine, u32* ctr) {
    __shared__ u32 sd[1024];
    int t = threadIdx.x;
    u32 cc = ctr[2], rem = ctr[3];
    u32 v = fine[1023 - t];
    sd[t] = v;
    __syncthreads();
    for (int off = 1; off < 1024; off <<= 1) {
        u32 tmp = (t >= off) ? sd[t - off] : 0u;
        __syncthreads();
        sd[t] += tmp;
        __syncthreads();
    }
    u32 incl = sd[t], excl = incl - v;
    if (incl >= rem && excl < rem)
        ctr[1] = ((cc << 10) + (u32)(1023 - t)) << 10;
}

__global__ void compact_kernel(const float* __restrict__ probs, u32* ctr,
                               u64* __restrict__ cand, int nfg) {
    int i = blockIdx.x * blockDim.x + threadIdx.x;
    if (i >= nfg) return;
    u32 pivot = ctr[1];
    float v = probs[(i >> 1) * 3 + 1 + (i & 1)];
    u32 bits = __float_as_uint(v);
    if (bits >= pivot) {
        u32 pos = atomicAdd(&ctr[0], 1u);
        if (pos < 8192u) cand[pos] = ((u64)bits << 32) | (u64)(~(u32)i);
    }
}

/* exact descending stable position via rank-by-counting (keys unique) */
__global__ __launch_bounds__(256) void rank_kernel(const u64* __restrict__ cand,
                                                   const u32* __restrict__ ctr,
                                                   u64* __restrict__ ranked) {
    __shared__ u64 tile[256];
    int t = threadIdx.x;
    int i = blockIdx.x * 256 + t;
    u32 M = ctr[0]; if (M > 8192u) M = 8192u;
    u64 key = (i < (int)M) ? cand[i] : 0ull;
    int rank = 0;
    for (u32 base = 0; base < M; base += 256) {
        u32 s = base + t;
        tile[t] = (s < M) ? cand[s] : 0ull;
        __syncthreads();
        #pragma unroll 8
        for (int q = 0; q < 256; ++q) rank += (tile[q] > key) ? 1 : 0;
        __syncthreads();
    }
    if (i < (int)M && rank < PRE_NMS) ranked[rank] = key;
}

__global__ void rois_kernel(const u64* __restrict__ skeys,
                            const float4* __restrict__ deltas4,
                            const float4* __restrict__ anchors4,
                            float* __restrict__ out,
                            float4* __restrict__ boxes,
                            float* __restrict__ areas,
                            int* __restrict__ gid,
                            int n_anch) {
    int s = blockIdx.x * blockDim.x + threadIdx.x;
    if (s >= PRE_NMS) return;
    u64 key = skeys[s];
    u32 bits = (u32)(key >> 32);
    u32 flat = ~((u32)key);
    float score = __uint_as_float(bits);
    int p = (int)(flat >> 1);
    int cls = (int)(flat & 1u) + 1;
    int b = p / n_anch;
    int aidx = p - b * n_anch;
    float4 a = anchors4[aidx];
    float4 d = deltas4[p];
    float d0 = d.x * 0.1f, d1 = d.y * 0.1f, d2 = d.z * 0.2f, d3 = d.w * 0.2f;
    float y1 = a.x * (1.0f / 512.0f), x1 = a.y * (1.0f / 512.0f);
    float y2 = a.z * (1.0f / 512.0f), x2 = a.w * (1.0f / 512.0f);
    float h = y2 - y1, w = x2 - x1;
    float cy = y1 + 0.5f * h + d0 * h;
    float cx = x1 + 0.5f * w + d1 * w;
    h = h * expf(d2);
    w = w * expf(d3);
    float ry1 = (cy - 0.5f * h) * 512.0f;
    float rx1 = (cx - 0.5f * w) * 512.0f;
    float ry2 = (cy - 0.5f * h + h) * 512.0f;
    float rx2 = (cx - 0.5f * w + w) * 512.0f;
    ry1 = fminf(fmaxf(ry1, 0.0f), 512.0f);
    rx1 = fminf(fmaxf(rx1, 0.0f), 512.0f);
    ry2 = fminf(fmaxf(ry2, 0.0f), 512.0f);
    rx2 = fminf(fmaxf(rx2, 0.0f), 512.0f);
    out[s * 6 + 0] = ry1;
    out[s * 6 + 1] = rx1;
    out[s * 6 + 2] = ry2;
    out[s * 6 + 3] = rx2;
    out[s * 6 + 4] = score;
    out[PRE_NMS * 6 + s] = (float)cls;
    out[PRE_NMS * 7 + s] = (float)b;
    int g = b * 3 + cls;
    float gf = (float)g * 4096.0f;
    float4 bb = make_float4(ry1 + gf, rx1 + gf, ry2 + gf, rx2 + gf);
    boxes[s] = bb;
    areas[s] = (bb.z - bb.x + 1.0f) * (bb.w - bb.y + 1.0f);
    gid[s] = g;
}

/* One block per (batch,class) group; cross-group IoU exactly 0 (offset 4096).
   Parallel mask build into LDS (off serial chain), then register-prefetched
   serial scan: ~6 u64 VALU ops per row on the chain, no memory latency. */
__global__ __launch_bounds__(256) void group_nms_kernel(const float4* __restrict__ boxes,
                                                        const float* __restrict__ areas,
                                                        const int* __restrict__ gid,
                                                        float* __restrict__ out) {
    __shared__ u64 sWords[96];
    __shared__ int bpre[96];
    __shared__ unsigned short list[PRE_NMS];                 /* 12 KB */
    __shared__ float y1s[KMAX], x1s[KMAX], y2s[KMAX], x2s[KMAX], ars[KMAX]; /* 10 KB */
    __shared__ u64 maskm[KMAX * WMAX + 64];                  /* 33 KB (+lane-overrun pad) */
    __shared__ int sK;
    int g = blockIdx.x, t = threadIdx.x, lane = t & 63, wv = t >> 6;

    /* Phase A1: per-64-block membership bitmasks, parallel over 4 waves */
    for (int blk = wv; blk < NBLK; blk += 4) {
        int s = (blk << 6) | lane;
        bool f = (s < PRE_NMS) && (gid[s] == g);
        u64 bal = __ballot(f);
        if (lane == 0) sWords[blk] = bal;
    }
    __syncthreads();

    /* Phase A2: exclusive prefix over 94 block counts (wave 0, shfl scan) */
    if (t < 64) {
        int c0 = (int)__popcll(sWords[lane]);
        int c1 = (lane < NBLK - 64) ? (int)__popcll(sWords[64 + lane]) : 0;
        int i0 = c0, i1 = c1;
        #pragma unroll
        for (int off = 1; off < 64; off <<= 1) {
            int a = __shfl_up(i0, off); if (lane >= off) i0 += a;
            int b = __shfl_up(i1, off); if (lane >= off) i1 += b;
        }
        int tot0 = __shfl(i0, 63), tot1 = __shfl(i1, 63);
        bpre[lane] = i0 - c0;
        if (lane < 32) bpre[64 + lane] = tot0 + ((lane < NBLK - 64) ? (i1 - c1) : tot1);
        if (lane == 0) sK = tot0 + tot1;
    }
    __syncthreads();
    int K = sK;
    if (K == 0) return;
    bool fast = (K <= KMAX);

    /* Phase A3: scatter list + stage SoA (parallel, latency-hidden) */
    for (int blk = wv; blk < NBLK; blk += 4) {
        int s = (blk << 6) | lane;
        u64 w = sWords[blk];
        if ((w >> lane) & 1ull) {
            int pos = bpre[blk] + (int)__popcll(w & ((1ull << lane) - 1ull));
            list[pos] = (unsigned short)s;
            if (fast) {
                float4 bb = boxes[s];
                y1s[pos] = bb.x; x1s[pos] = bb.y; y2s[pos] = bb.z; x2s[pos] = bb.w;
                ars[pos] = areas[s];
            }
        }
    }
    __syncthreads();
    int W = (K + 63) >> 6;

    if (fast) {
        /* Phase B: all 256 threads build K x 8 word mask matrix in LDS */
        for (int item = t; item < (K << 3); item += 256) {
            int r = item >> 3, c = item & 7;
            int j0 = c << 6;
            int qs = r + 1 - j0; if (qs < 0) qs = 0;
            int qe = K - j0; if (qe > 64) qe = 64;
            u64 word = 0ull;
            float ry1 = y1s[r], rx1 = x1s[r], ry2 = y2s[r], rx2 = x2s[r], ra = ars[r];
            for (int q = qs; q < qe; ++q) {
                int cc = j0 + q;
                float ih = fminf(ry2, y2s[cc]) - fmaxf(ry1, y1s[cc]) + 1.0f;
                float iw = fminf(rx2, x2s[cc]) - fmaxf(rx1, x1s[cc]) + 1.0f;
                ih = fmaxf(ih, 0.0f); iw = fmaxf(iw, 0.0f);
                if (3.0f * ih * iw >= ra + ars[cc]) word |= (1ull << q);
            }
            maskm[(r << 3) + c] = word;
        }
        __syncthreads();

        /* Phase C: serial scan, wave 0; chunk-8 prefetch keeps loads off the chain */
        if (t >= 64) return;
        u64 remv = 0ull;   /* lane l holds suppression word l (l < 8 meaningful) */
        for (int w = 0; w < W; ++w) {
            int r0 = w << 6;
            int rend = K - r0; if (rend > 64) rend = 64;
            u64 curw = __shfl(remv, w);
            u64 kb = 0ull;
            for (int b0 = 0; b0 < rend; b0 += 8) {
                int n = rend - b0; if (n > 8) n = 8;
                u64 mrow[8], dg[8];
                #pragma unroll
                for (int j = 0; j < 8; ++j) {
                    int rr = r0 + b0 + ((j < n) ? j : 0);
                    mrow[j] = maskm[(rr << 3) + lane];  /* pad covers lane>=8 overrun */
                    dg[j]   = maskm[(rr << 3) + w];     /* uniform addr: broadcast */
                }
                #pragma unroll
                for (int j = 0; j < 8; ++j) {
                    if (j < n) {
                        int b = b0 + j;
                        u64 km = ((curw >> b) & 1ull) ? 0ull : ~0ull;
                        curw |= dg[j] & km;
                        remv |= mrow[j] & km;
                        kb |= km & (1ull << b);
                    }
                }
            }
            if (lane < rend)
                out[(int)list[r0 + lane] * 6 + 5] = ((kb >> lane) & 1ull) ? 1.0f : 0.0f;
        }
    } else {
        /* fallback K > KMAX (statistically impossible): iterative from global */
        if (t >= 64) return;
        u64 remv0 = 0ull, remv1 = 0ull;
        for (int w = 0; w < W; ++w) {
            int r0 = w << 6;
            int rend = K - r0; if (rend > 64) rend = 64;
            u64 cur = (w < 64) ? __ballot((remv0 >> w) & 1ull)
                               : __ballot((remv1 >> (w - 64)) & 1ull);
            u64 kb = 0ull;
            for (int b = 0; b < rend; ++b) {
                int r = r0 + b;
                bool sup = (cur >> b) & 1ull;
                kb |= (sup ? 0ull : 1ull) << b;
                if (!sup) {
                    int sr = list[r];
                    float4 rb = boxes[sr];
                    float ra = areas[sr];
                    for (int k = w; k < W; ++k) {
                        int c = (k << 6) + lane;
                        bool o = false;
                        if (c < K && c > r) {
                            int sc = list[c];
                            float4 cb = boxes[sc];
                            float ih = fminf(rb.z, cb.z) - fmaxf(rb.x, cb.x) + 1.0f;
                            float iw = fminf(rb.w, cb.w) - fmaxf(rb.y, cb.y) + 1.0f;
                            ih = fmaxf(ih, 0.0f); iw = fmaxf(iw, 0.0f);
                            o = (3.0f * ih * iw >= ra + areas[sc]);
                        }
                        if (o) { if (k < 64) remv0 |= 1ull << k; else remv1 |= 1ull << (k - 64); }
                    }
                    cur = (w < 64) ? __ballot((remv0 >> w) & 1ull)
                                   : __ballot((remv1 >> (w - 64)) & 1ull);
                }
            }
            if (lane < rend)
                out[(int)list[r0 + lane] * 6 + 5] = ((kb >> lane) & 1ull) ? 1.0f : 0.0f;
        }
    }
}

extern "C" void kernel_launch(void* const* d_in, const int* in_sizes, int n_in,
                              void* d_out, int out_size, void* d_ws, size_t ws_size,
                              hipStream_t stream) {
    const float* probs   = (const float*)d_in[0];
    const float* deltas  = (const float*)d_in[1];
    const float* anchors = (const float*)d_in[2];
    int n_prop = in_sizes[1] / 4;        /* 522240 */
    int n_anch = in_sizes[2] / 4;        /* 65280  */
    int nfg    = n_prop * 2;             /* 1044480 */

    char* ws = (char*)d_ws;
    u32*    ctr    = (u32*)(ws + CTR_OFF);
    u32*    coarse = (u32*)(ws + COARSE_OFF);
    u32*    fine   = (u32*)(ws + FINE_OFF);
    u64*    cand   = (u64*)(ws + CAND_OFF);
    u64*    ranked = (u64*)(ws + RANK_OFF);
    float4* boxes  = (float4*)(ws + BOX_OFF);
    float*  areas  = (float*)(ws + AREA_OFF);
    int*    gid    = (int*)(ws + GID_OFF);
    float*  out    = (float*)d_out;

    /* zero ctr+coarse+fine: (64+1024+1024) u32 = 528 uint4 */
    zero_kernel<<<3, 256, 0, stream>>>((uint4*)ws, 528);
    coarse_hist_kernel<<<64, 1024, 0, stream>>>(probs, coarse, nfg);
    pivot1_kernel<<<1, 1024, 0, stream>>>(coarse, ctr);
    fine_hist_kernel<<<64, 1024, 0, stream>>>(probs, ctr, fine, nfg);
    pivot2_kernel<<<1, 1024, 0, stream>>>(fine, ctr);
    compact_kernel<<<(nfg + 255) / 256, 256, 0, stream>>>(probs, ctr, cand, nfg);
    rank_kernel<<<32, 256, 0, stream>>>(cand, ctr, ranked);
    rois_kernel<<<(PRE_NMS + 255) / 256, 256, 0, stream>>>(
        ranked, (const float4*)deltas, (const float4*)anchors, out, boxes, areas, gid, n_anch);
    group_nms_kernel<<<NGROUPS, 256, 0, stream>>>(boxes, areas, gid, out);
}